// Round 6
// baseline (956.954 us; speedup 1.0000x reference)
//
#include <hip/hip_runtime.h>
#include <stdint.h>

// K=6, B=128, N=65536, D=256, fp32 in/out.
// d_out = [soft_labels (K*B*N)] ++ [sim (K*B*N)] fp32.
// d_ws: ahi (393216 B) + alo (393216 B) + cand (31457280 B) ~= 32.2 MB.
//
// R6 == R5 == R4 == R3 (R3-R5 hit GPUAcquisitionTimeout; never measured).
// R3 vs R2: R2's launch_bounds(512,8) capped unified VGPR+AGPR at 64 ->
// staging spilled to scratch -> hbm_bytes 0.77->1.34 GB -> slower despite 81%
// occupancy. R3: 256-thr blocks (4 waves), tile 128x64, BK=32, 24 KB LDS,
// launch_bounds(256,4) (cap 128 regs, no spill), 4-5 independent blocks/CU
// for cross-block latency hiding. cand writes block-coalesced.

#define KP 6
#define BROWS 128
#define NCOLS 65536
#define DDIM 256
#define BN 64
#define BK 32
#define NBLK (NCOLS / BN)   // 1024
#define T1 256

typedef short bf16x8 __attribute__((ext_vector_type(8)));
typedef float f32x4 __attribute__((ext_vector_type(4)));

__device__ __forceinline__ uint32_t f2bf(float f) {            // fp32 -> bf16 RNE
  uint32_t u = __float_as_uint(f);
  return (u + 0x7FFFu + ((u >> 16) & 1u)) >> 16;
}
__device__ __forceinline__ float bf2f(uint32_t h) { return __uint_as_float(h << 16); }

// monotonic key: larger value => larger key; ties break toward LOWER index
// (matches jax.lax.top_k), via ~idx in low bits.
__device__ __forceinline__ unsigned long long mkkey(float v, uint32_t idx) {
  uint32_t u = __float_as_uint(v);
  uint32_t ov = ((int32_t)u < 0) ? ~u : (u | 0x80000000u);
  return ((unsigned long long)ov << 32) | (uint32_t)(~idx);
}
__device__ __forceinline__ float keyval(unsigned long long k) {
  uint32_t ov = (uint32_t)(k >> 32);
  uint32_t u = (ov & 0x80000000u) ? (ov ^ 0x80000000u) : ~ov;
  return __uint_as_float(u);
}
__device__ __forceinline__ uint32_t keyidx(unsigned long long k) { return ~(uint32_t)k; }

__device__ __forceinline__ void ins5(unsigned long long* t, unsigned long long key) {
  if (key > t[4]) {
    t[4] = key;
#pragma unroll
    for (int q = 4; q > 0; --q)
      if (t[q] > t[q - 1]) { unsigned long long tmp = t[q]; t[q] = t[q - 1]; t[q - 1] = tmp; }
  }
}

// XOR-swizzled LDS offset for [R][32] bf16 row-major tiles (64 B rows).
// Measured R2: conflicts 688K cyc (~0.3%) with this scheme -> adequate.
__device__ __forceinline__ int ldsOff(int row, int colByte) {
  return (row << 6) + (colByte ^ (((row >> 1) & 3) << 4));
}

// ---------------- kernel 0: L2-normalize rows of part_features, split fp32 -> bf16 hi/lo
__global__ __launch_bounds__(256) void norm_split(const float* __restrict__ part,
                                                  uint16_t* __restrict__ ahi,
                                                  uint16_t* __restrict__ alo) {
  int row = blockIdx.x;             // k*128 + b
  int t = threadIdx.x;              // = d (DDIM == 256)
  float x = part[(size_t)row * DDIM + t];
  float ss = x * x;
#pragma unroll
  for (int off = 32; off; off >>= 1) ss += __shfl_down(ss, off, 64);
  __shared__ float wsum[4];
  __shared__ float nrm;
  if ((t & 63) == 0) wsum[t >> 6] = ss;
  __syncthreads();
  if (t == 0) nrm = fmaxf(sqrtf(wsum[0] + wsum[1] + wsum[2] + wsum[3]), 1e-12f);
  __syncthreads();
  float xf = x / nrm;
  uint32_t h = f2bf(xf);
  uint32_t l = f2bf(xf - bf2f(h));
  ahi[(size_t)row * DDIM + t] = (uint16_t)h;
  alo[(size_t)row * DDIM + t] = (uint16_t)l;
}

// ---------------- kernel 1: split-bf16 MFMA GEMM tile (128 x 64) + sim write +
// soft zeros + in-register per-tile top-5 -> candidate buffer
__global__ __launch_bounds__(T1, 4) void gemm_topk(const float* __restrict__ memB,
                                                   const uint16_t* __restrict__ ahi,
                                                   const uint16_t* __restrict__ alo,
                                                   float* __restrict__ soft,
                                                   float* __restrict__ sim,
                                                   unsigned long long* __restrict__ cand) {
  __shared__ __align__(16) char smem[24576];
  char* AH = smem;             // [128][32] bf16 hi (8 KB)
  char* AL = smem + 8192;      // [128][32] bf16 lo (8 KB)
  char* BH = smem + 16384;     // [ 64][32] bf16 hi (4 KB)
  char* BL = smem + 20480;     // [ 64][32] bf16 lo (4 KB)

  const int k = blockIdx.y;
  const int nb = blockIdx.x;
  const int n0 = nb * BN;
  const int tid = threadIdx.x;
  const int lane = tid & 63;
  const int wv = tid >> 6;        // 0..3
  const int wm = wv >> 1;         // 0..1  (64 rows each)
  const int wn = wv & 1;          // 0..1  (32 cols each)
  const int l15 = lane & 15;
  const int lq = lane >> 4;       // 0..3

  const float* Bbase = memB + ((size_t)k * NCOLS + n0) * DDIM;
  const uint16_t* AHg = ahi + (size_t)k * BROWS * DDIM;
  const uint16_t* ALg = alo + (size_t)k * BROWS * DDIM;

  f32x4 acc[4][2];
#pragma unroll
  for (int mf = 0; mf < 4; ++mf)
#pragma unroll
    for (int nf = 0; nf < 2; ++nf) acc[mf][nf] = (f32x4)(0.0f);

  float4 rb[2];           // B staging: 64x32 fp32 / 256 thr = 2 float4
  uint4 rah[2], ral[2];   // A staging: 128x32 bf16 / 256 thr = 2 uint4 each

  auto loadChunk = [&](int c) {
#pragma unroll
    for (int p = 0; p < 2; ++p) {
      int idx = p * T1 + tid;            // 0..511 over 64x32/4
      int r = idx >> 3, cl = (idx & 7) * 4;
      rb[p] = *(const float4*)(Bbase + (size_t)r * DDIM + c * BK + cl);
    }
#pragma unroll
    for (int p = 0; p < 2; ++p) {
      int idx = p * T1 + tid;            // 0..511 over 128x32/8
      int r = idx >> 2, cl = (idx & 3) * 8;
      rah[p] = *(const uint4*)(AHg + (size_t)r * DDIM + c * BK + cl);
      ral[p] = *(const uint4*)(ALg + (size_t)r * DDIM + c * BK + cl);
    }
  };

  auto storeStage = [&]() {
#pragma unroll
    for (int p = 0; p < 2; ++p) {
      int idx = p * T1 + tid;
      int r = idx >> 3, cl = (idx & 7) * 4;
      uint32_t h0 = f2bf(rb[p].x), h1 = f2bf(rb[p].y), h2 = f2bf(rb[p].z), h3 = f2bf(rb[p].w);
      uint32_t l0 = f2bf(rb[p].x - bf2f(h0));
      uint32_t l1 = f2bf(rb[p].y - bf2f(h1));
      uint32_t l2 = f2bf(rb[p].z - bf2f(h2));
      uint32_t l3 = f2bf(rb[p].w - bf2f(h3));
      int off = ldsOff(r, cl * 2);
      *(uint2*)(BH + off) = make_uint2(h0 | (h1 << 16), h2 | (h3 << 16));
      *(uint2*)(BL + off) = make_uint2(l0 | (l1 << 16), l2 | (l3 << 16));
    }
#pragma unroll
    for (int p = 0; p < 2; ++p) {
      int idx = p * T1 + tid;
      int r = idx >> 2, cl = (idx & 3) * 8;
      int off = ldsOff(r, cl * 2);
      *(uint4*)(AH + off) = rah[p];
      *(uint4*)(AL + off) = ral[p];
    }
  };

  loadChunk(0);
#pragma unroll
  for (int c = 0; c < 8; ++c) {
    if (c) __syncthreads();              // previous chunk's readers done
    storeStage();
    __syncthreads();
    if (c < 7) loadChunk(c + 1);         // prefetch next chunk under compute
    const int cb = lq * 16;              // 16B slot within 64B row
    bf16x8 bfh[2], bfl[2];
#pragma unroll
    for (int nf = 0; nf < 2; ++nf) {
      int r = wn * 32 + nf * 16 + l15;
      bfh[nf] = *(const bf16x8*)(BH + ldsOff(r, cb));
      bfl[nf] = *(const bf16x8*)(BL + ldsOff(r, cb));
    }
#pragma unroll
    for (int mf = 0; mf < 4; ++mf) {
      int r = wm * 64 + mf * 16 + l15;
      bf16x8 afh = *(const bf16x8*)(AH + ldsOff(r, cb));
      bf16x8 afl = *(const bf16x8*)(AL + ldsOff(r, cb));
#pragma unroll
      for (int nf = 0; nf < 2; ++nf) {
        acc[mf][nf] = __builtin_amdgcn_mfma_f32_16x16x32_bf16(afh, bfh[nf], acc[mf][nf], 0, 0, 0);
        acc[mf][nf] = __builtin_amdgcn_mfma_f32_16x16x32_bf16(afh, bfl[nf], acc[mf][nf], 0, 0, 0);
        acc[mf][nf] = __builtin_amdgcn_mfma_f32_16x16x32_bf16(afl, bfh[nf], acc[mf][nf], 0, 0, 0);
      }
    }
  }

  // ---- epilogue: sim stores (C frags: col=lane&15, row=(lane>>4)*4+reg) ----
#pragma unroll
  for (int mf = 0; mf < 4; ++mf)
#pragma unroll
    for (int nf = 0; nf < 2; ++nf)
#pragma unroll
      for (int j = 0; j < 4; ++j) {
        int row = wm * 64 + mf * 16 + lq * 4 + j;
        int ccol = wn * 32 + nf * 16 + l15;
        sim[(size_t)(k * BROWS + row) * NCOLS + n0 + ccol] = acc[mf][nf][j];
      }
  // zeros for soft_labels tile (coalesced float4): 128x64 floats
  {
    const size_t softbase = (size_t)(k * BROWS) * NCOLS + n0;
    float4 z4 = make_float4(0.f, 0.f, 0.f, 0.f);
#pragma unroll
    for (int p = 0; p < 8; ++p) {
      int e = (p * T1 + tid) * 4;     // 8192 floats
      int r = e >> 6, ccol = e & 63;
      *(float4*)(soft + softbase + (size_t)r * NCOLS + ccol) = z4;
    }
  }

  // ---- in-register per-row top-5 over this tile's 32 cols per wave ----
  __syncthreads();                            // staging LDS dead -> reuse for CAND
  unsigned long long* CAND = (unsigned long long*)smem;  // [128 rows][2 wn][5] = 10 KB
#pragma unroll
  for (int mf = 0; mf < 4; ++mf) {
#pragma unroll
    for (int j = 0; j < 4; ++j) {
      int row = wm * 64 + mf * 16 + lq * 4 + j;
      unsigned long long k0 = mkkey(acc[mf][0][j], (uint32_t)(n0 + wn * 32 + l15));
      unsigned long long k1 = mkkey(acc[mf][1][j], (uint32_t)(n0 + wn * 32 + 16 + l15));
      unsigned long long w0, w1, w2, w3, w4;
#pragma unroll
      for (int rd = 0; rd < 5; ++rd) {
        unsigned long long km = k0 > k1 ? k0 : k1;
#pragma unroll
        for (int s = 1; s < 16; s <<= 1) {     // reduce within 16-lane row-group
          unsigned long long o = __shfl_xor(km, s, 64);
          if (o > km) km = o;
        }
        if (rd == 0) w0 = km; else if (rd == 1) w1 = km; else if (rd == 2) w2 = km;
        else if (rd == 3) w3 = km; else w4 = km;
        if (k0 == km) k0 = 0; else if (k1 == km) k1 = 0;   // remove winner (keys unique)
      }
      if (l15 == 0) {
        unsigned long long* dst = &CAND[(row * 2 + wn) * 5];
        dst[0] = w0; dst[1] = w1; dst[2] = w2; dst[3] = w3; dst[4] = w4;
      }
    }
  }
  __syncthreads();
  if (tid < BROWS) {   // merge the 2 wn-lists per row; block-coalesced cand write
    unsigned long long m[5] = {0, 0, 0, 0, 0};
#pragma unroll
    for (int g = 0; g < 2; ++g)
#pragma unroll
      for (int j = 0; j < 5; ++j) ins5(m, CAND[(tid * 2 + g) * 5 + j]);
    size_t cb = ((size_t)(k * NBLK + nb) * BROWS + tid) * 5;
#pragma unroll
    for (int j = 0; j < 5; ++j) cand[cb + j] = m[j];
  }
}

// ---------------- kernel 2: reduce candidates per row -> top-5 softmax -> scatter
__global__ __launch_bounds__(256) void topk_softmax(const unsigned long long* __restrict__ cand,
                                                    float* __restrict__ soft) {
  int k = blockIdx.x >> 7;            // row = k*128 + b
  int b = blockIdx.x & 127;
  unsigned long long t5[5] = {0, 0, 0, 0, 0};
  for (int nb = threadIdx.x; nb < NBLK; nb += 256) {
    const unsigned long long* p = cand + ((size_t)(k * NBLK + nb) * BROWS + b) * 5;
#pragma unroll
    for (int j = 0; j < 5; ++j) ins5(t5, p[j]);
  }
  __shared__ unsigned long long lds[256 * 5];
#pragma unroll
  for (int j = 0; j < 5; ++j) lds[threadIdx.x * 5 + j] = t5[j];
  __syncthreads();
  if (threadIdx.x < 64) {
    unsigned long long m[5] = {0, 0, 0, 0, 0};
#pragma unroll
    for (int g = 0; g < 4; ++g)
#pragma unroll
      for (int j = 0; j < 5; ++j) ins5(m, lds[(threadIdx.x * 4 + g) * 5 + j]);
#pragma unroll
    for (int off = 1; off < 64; off <<= 1) {   // butterfly merge of sorted 5-lists
      unsigned long long o[5];
#pragma unroll
      for (int j = 0; j < 5; ++j) o[j] = __shfl_xor(m[j], off, 64);
      unsigned long long out[5];
      int a = 0, b2 = 0;
#pragma unroll
      for (int r = 0; r < 5; ++r) out[r] = (m[a] >= o[b2]) ? m[a++] : o[b2++];
#pragma unroll
      for (int j = 0; j < 5; ++j) m[j] = out[j];
    }
    if (threadIdx.x == 0) {
      float v[5]; uint32_t ix[5];
#pragma unroll
      for (int j = 0; j < 5; ++j) { v[j] = keyval(m[j]); ix[j] = keyidx(m[j]); }
      float mx = v[0];     // m[0] is the max
      float e[5], Z = 0.f;
#pragma unroll
      for (int j = 0; j < 5; ++j) { e[j] = expf((v[j] - mx) * (1.0f / 3.0f)); Z += e[j]; }
      float invZ = 1.0f / Z;
      size_t row = (size_t)k * BROWS + b;
#pragma unroll
      for (int j = 0; j < 5; ++j) soft[row * NCOLS + ix[j]] = e[j] * invZ;
    }
  }
}

extern "C" void kernel_launch(void* const* d_in, const int* in_sizes, int n_in,
                              void* d_out, int out_size, void* d_ws, size_t ws_size,
                              hipStream_t stream) {
  const float* part = (const float*)d_in[0];    // [6,128,256]
  const float* memB = (const float*)d_in[1];    // [6,65536,256]
  float* soft = (float*)d_out;                                  // [6,128,65536]
  float* sim = soft + (size_t)KP * BROWS * NCOLS;               // [6,128,65536]

  uint16_t* ahi = (uint16_t*)d_ws;
  uint16_t* alo = ahi + (size_t)KP * BROWS * DDIM;
  unsigned long long* cand =
      (unsigned long long*)((char*)d_ws + (size_t)2 * KP * BROWS * DDIM * sizeof(uint16_t));

  norm_split<<<KP * BROWS, 256, 0, stream>>>(part, ahi, alo);
  dim3 g1(NBLK, KP);
  gemm_topk<<<g1, T1, 0, stream>>>(memB, ahi, alo, soft, sim, cand);
  topk_softmax<<<KP * BROWS, 256, 0, stream>>>(cand, soft);
}

// Round 9
// 771.071 us; speedup vs baseline: 1.2411x; 1.2411x over previous
//
#include <hip/hip_runtime.h>
#include <stdint.h>

// K=6, B=128, N=65536, D=256, fp32 in/out.
// d_out = [soft_labels (K*B*N)] ++ [sim (K*B*N)] fp32.
// d_ws: A-blocked tiles (786432 B) + cand (15728640 B) ~= 16.5 MB.
//
// R9 == R8 == R7 (R7/R8 hit GPUAcquisitionTimeout; never measured).
// R7: lesson from R2/R3 (both spilled under forced occupancy caps; WRITE-only
// inflation = spill signature): cut register DEMAND structurally instead.
// A is pre-split+pre-swizzled into blocked 8KB tiles by norm_split and staged
// with global_load_lds width=16 (zero staging regs); only B round-trips
// through 8 regs for fp32->bf16 hi/lo split. 128x128 tile (memB read once),
// BK=32, single-buffer 32KB LDS, m97-style 2-barrier loop, 8 waves,
// launch_bounds(512,6) -> 3 blocks/CU for cross-block drain overlap.

#define KP 6
#define BROWS 128
#define NCOLS 65536
#define DDIM 256
#define BN 128
#define BK 32
#define NBLK (NCOLS / BN)   // 512
#define NCH (DDIM / BK)     // 8
#define T1 512

typedef short bf16x8 __attribute__((ext_vector_type(8)));
typedef float f32x4 __attribute__((ext_vector_type(4)));

__device__ __forceinline__ uint32_t f2bf(float f) {            // fp32 -> bf16 RNE
  uint32_t u = __float_as_uint(f);
  return (u + 0x7FFFu + ((u >> 16) & 1u)) >> 16;
}
__device__ __forceinline__ float bf2f(uint32_t h) { return __uint_as_float(h << 16); }

// monotonic key: larger value => larger key; ties break toward LOWER index
// (matches jax.lax.top_k), via ~idx in low bits.
__device__ __forceinline__ unsigned long long mkkey(float v, uint32_t idx) {
  uint32_t u = __float_as_uint(v);
  uint32_t ov = ((int32_t)u < 0) ? ~u : (u | 0x80000000u);
  return ((unsigned long long)ov << 32) | (uint32_t)(~idx);
}
__device__ __forceinline__ float keyval(unsigned long long k) {
  uint32_t ov = (uint32_t)(k >> 32);
  uint32_t u = (ov & 0x80000000u) ? (ov ^ 0x80000000u) : ~ov;
  return __uint_as_float(u);
}
__device__ __forceinline__ uint32_t keyidx(unsigned long long k) { return ~(uint32_t)k; }

__device__ __forceinline__ void ins5(unsigned long long* t, unsigned long long key) {
  if (key > t[4]) {
    t[4] = key;
#pragma unroll
    for (int q = 4; q > 0; --q)
      if (t[q] > t[q - 1]) { unsigned long long tmp = t[q]; t[q] = t[q - 1]; t[q - 1] = tmp; }
  }
}

// XOR-swizzled offset within a [128][32] bf16 tile (64 B rows). Same formula
// used by norm_split (A tile writer), writeB (LDS store), and frag ds_reads.
// <=2-way bank conflict on ds_read_b128 fragments (free per m136).
__device__ __forceinline__ int ldsOff(int row, int colByte) {
  return (row << 6) + (colByte ^ (((row >> 1) & 3) << 4));
}

__device__ __forceinline__ void gload16(const void* g, void* l) {
  __builtin_amdgcn_global_load_lds((const __attribute__((address_space(1))) uint32_t*)g,
                                   (__attribute__((address_space(3))) uint32_t*)l, 16, 0, 0);
}

// ---------------- kernel 0: L2-normalize A rows, split fp32 -> bf16 hi/lo,
// write into blocked+swizzled 8KB tiles: ws[(k*NCH+c)*16384 + {0|8192} + swzOff]
__global__ __launch_bounds__(256) void norm_split(const float* __restrict__ part,
                                                  char* __restrict__ wsA) {
  int row = blockIdx.x;             // k*128 + b
  int k = row >> 7, b = row & 127;
  int t = threadIdx.x;              // = d (DDIM == 256)
  float x = part[(size_t)row * DDIM + t];
  float ss = x * x;
#pragma unroll
  for (int off = 32; off; off >>= 1) ss += __shfl_down(ss, off, 64);
  __shared__ float wsum[4];
  __shared__ float nrm;
  if ((t & 63) == 0) wsum[t >> 6] = ss;
  __syncthreads();
  if (t == 0) nrm = fmaxf(sqrtf(wsum[0] + wsum[1] + wsum[2] + wsum[3]), 1e-12f);
  __syncthreads();
  float xf = x / nrm;
  uint32_t h = f2bf(xf);
  uint32_t l = f2bf(xf - bf2f(h));
  int c = t >> 5, col = t & 31;
  char* tb = wsA + (size_t)(k * NCH + c) * 16384;
  int off = ldsOff(b, col * 2);
  *(uint16_t*)(tb + off) = (uint16_t)h;
  *(uint16_t*)(tb + 8192 + off) = (uint16_t)l;
}

// ---------------- kernel 1: split-bf16 MFMA GEMM tile (128 x 128) + sim write +
// soft zeros + in-register per-tile top-5 -> candidate buffer
__global__ __launch_bounds__(T1, 6) void gemm_topk(const float* __restrict__ memB,
                                                   const char* __restrict__ wsA,
                                                   float* __restrict__ soft,
                                                   float* __restrict__ sim,
                                                   unsigned long long* __restrict__ cand) {
  __shared__ __align__(16) char smem[32768];
  char* AH = smem;             // [128][32] bf16 hi (8 KB, swizzled)
  char* AL = smem + 8192;
  char* BH = smem + 16384;
  char* BL = smem + 24576;

  const int k = blockIdx.y;
  const int nb = blockIdx.x;
  const int n0 = nb * BN;
  const int tid = threadIdx.x;
  const int lane = tid & 63;
  const int wv = tid >> 6;        // 0..7
  const int wm = wv >> 2;         // 0..1  (64 rows each)
  const int wn = wv & 3;          // 0..3  (32 cols each)
  const int l15 = lane & 15;
  const int lq = lane >> 4;       // 0..3

  const float* Bbase = memB + ((size_t)k * NCOLS + n0) * DDIM;
  const char* Abase = wsA + (size_t)k * NCH * 16384;

  f32x4 acc[4][2];
#pragma unroll
  for (int mf = 0; mf < 4; ++mf)
#pragma unroll
    for (int nf = 0; nf < 2; ++nf) acc[mf][nf] = (f32x4)(0.0f);

  float4 rb[2];           // only staging: B chunk 128x32 fp32 / 512 thr = 2 float4

  auto loadB = [&](int c) {
#pragma unroll
    for (int p = 0; p < 2; ++p) {
      int idx = p * T1 + tid;            // over 128 rows x 8 float4-cols
      int r = idx >> 3, c4 = idx & 7;
      rb[p] = *(const float4*)(Bbase + (size_t)r * DDIM + c * BK + c4 * 4);
    }
  };

  auto writeB = [&]() {
#pragma unroll
    for (int p = 0; p < 2; ++p) {
      int idx = p * T1 + tid;
      int r = idx >> 3, c4 = idx & 7;
      uint32_t h0 = f2bf(rb[p].x), h1 = f2bf(rb[p].y), h2 = f2bf(rb[p].z), h3 = f2bf(rb[p].w);
      uint32_t l0 = f2bf(rb[p].x - bf2f(h0));
      uint32_t l1 = f2bf(rb[p].y - bf2f(h1));
      uint32_t l2 = f2bf(rb[p].z - bf2f(h2));
      uint32_t l3 = f2bf(rb[p].w - bf2f(h3));
      int off = ldsOff(r, c4 * 8);       // 8B store stays inside its 16B slot
      *(uint2*)(BH + off) = make_uint2(h0 | (h1 << 16), h2 | (h3 << 16));
      *(uint2*)(BL + off) = make_uint2(l0 | (l1 << 16), l2 | (l3 << 16));
    }
  };

  loadB(0);
#pragma unroll
  for (int c = 0; c < NCH; ++c) {
    if (c) __syncthreads();              // previous chunk's readers done
    {  // A via global_load_lds: tiles are pre-swizzled, LDS dest linear.
      const char* at = Abase + (size_t)c * 16384;
      gload16(at + tid * 16, AH + wv * 1024);          // AH 8KB = 512 x 16B
      gload16(at + 8192 + tid * 16, AL + wv * 1024);   // AL 8KB
    }
    writeB();                            // convert regs -> BH/BL (LDS)
    __syncthreads();                     // drains vmcnt: A landed, B visible
    if (c < NCH - 1) loadB(c + 1);       // prefetch next B chunk into regs
    const int cb = lq * 16;              // 16B K-slot within 64B row
    bf16x8 bfh[2], bfl[2];
#pragma unroll
    for (int nf = 0; nf < 2; ++nf) {
      int r = wn * 32 + nf * 16 + l15;
      bfh[nf] = *(const bf16x8*)(BH + ldsOff(r, cb));
      bfl[nf] = *(const bf16x8*)(BL + ldsOff(r, cb));
    }
#pragma unroll
    for (int mf = 0; mf < 4; ++mf) {     // A frags loaded per-mf to cap liveness
      int r = wm * 64 + mf * 16 + l15;
      bf16x8 afh = *(const bf16x8*)(AH + ldsOff(r, cb));
      bf16x8 afl = *(const bf16x8*)(AL + ldsOff(r, cb));
#pragma unroll
      for (int nf = 0; nf < 2; ++nf) {
        acc[mf][nf] = __builtin_amdgcn_mfma_f32_16x16x32_bf16(afh, bfh[nf], acc[mf][nf], 0, 0, 0);
        acc[mf][nf] = __builtin_amdgcn_mfma_f32_16x16x32_bf16(afh, bfl[nf], acc[mf][nf], 0, 0, 0);
        acc[mf][nf] = __builtin_amdgcn_mfma_f32_16x16x32_bf16(afl, bfh[nf], acc[mf][nf], 0, 0, 0);
      }
    }
  }

  // ---- epilogue: sim stores (C frags: col=lane&15, row=(lane>>4)*4+reg) ----
#pragma unroll
  for (int mf = 0; mf < 4; ++mf)
#pragma unroll
    for (int nf = 0; nf < 2; ++nf)
#pragma unroll
      for (int j = 0; j < 4; ++j) {
        int row = wm * 64 + mf * 16 + lq * 4 + j;
        int ccol = wn * 32 + nf * 16 + l15;
        sim[(size_t)(k * BROWS + row) * NCOLS + n0 + ccol] = acc[mf][nf][j];
      }
  // zeros for soft_labels tile (coalesced float4): 128x128 floats
  {
    const size_t softbase = (size_t)(k * BROWS) * NCOLS + n0;
    float4 z4 = make_float4(0.f, 0.f, 0.f, 0.f);
#pragma unroll
    for (int p = 0; p < 8; ++p) {
      int e = (p * T1 + tid) * 4;     // 16384 floats
      int r = e >> 7, ccol = e & 127;
      *(float4*)(soft + softbase + (size_t)r * NCOLS + ccol) = z4;
    }
  }

  // ---- in-register per-row top-5 over this tile's 32 cols per wave ----
  __syncthreads();                            // staging LDS dead -> reuse for CAND
  unsigned long long* CAND = (unsigned long long*)smem;  // [128 rows][4 wn][5] = 20 KB
#pragma unroll
  for (int mf = 0; mf < 4; ++mf) {
#pragma unroll
    for (int j = 0; j < 4; ++j) {
      int row = wm * 64 + mf * 16 + lq * 4 + j;
      unsigned long long k0 = mkkey(acc[mf][0][j], (uint32_t)(n0 + wn * 32 + l15));
      unsigned long long k1 = mkkey(acc[mf][1][j], (uint32_t)(n0 + wn * 32 + 16 + l15));
      unsigned long long w0, w1, w2, w3, w4;
#pragma unroll
      for (int rd = 0; rd < 5; ++rd) {
        unsigned long long km = k0 > k1 ? k0 : k1;
#pragma unroll
        for (int s = 1; s < 16; s <<= 1) {     // reduce within 16-lane row-group
          unsigned long long o = __shfl_xor(km, s, 64);
          if (o > km) km = o;
        }
        if (rd == 0) w0 = km; else if (rd == 1) w1 = km; else if (rd == 2) w2 = km;
        else if (rd == 3) w3 = km; else w4 = km;
        if (k0 == km) k0 = 0; else if (k1 == km) k1 = 0;   // remove winner (keys unique)
      }
      if (l15 == 0) {
        unsigned long long* dst = &CAND[(row * 4 + wn) * 5];
        dst[0] = w0; dst[1] = w1; dst[2] = w2; dst[3] = w3; dst[4] = w4;
      }
    }
  }
  __syncthreads();
  if (tid < BROWS) {   // merge the 4 wn-lists per row; block-coalesced cand write
    unsigned long long m[5] = {0, 0, 0, 0, 0};
#pragma unroll
    for (int g = 0; g < 4; ++g)
#pragma unroll
      for (int j = 0; j < 5; ++j) ins5(m, CAND[(tid * 4 + g) * 5 + j]);
    size_t cb = ((size_t)(k * NBLK + nb) * BROWS + tid) * 5;
#pragma unroll
    for (int j = 0; j < 5; ++j) cand[cb + j] = m[j];
  }
}

// ---------------- kernel 2: reduce candidates per row -> top-5 softmax -> scatter
__global__ __launch_bounds__(256) void topk_softmax(const unsigned long long* __restrict__ cand,
                                                    float* __restrict__ soft) {
  int k = blockIdx.x >> 7;            // row = k*128 + b
  int b = blockIdx.x & 127;
  unsigned long long t5[5] = {0, 0, 0, 0, 0};
  for (int nb = threadIdx.x; nb < NBLK; nb += 256) {
    const unsigned long long* p = cand + ((size_t)(k * NBLK + nb) * BROWS + b) * 5;
#pragma unroll
    for (int j = 0; j < 5; ++j) ins5(t5, p[j]);
  }
  __shared__ unsigned long long lds[256 * 5];
#pragma unroll
  for (int j = 0; j < 5; ++j) lds[threadIdx.x * 5 + j] = t5[j];
  __syncthreads();
  if (threadIdx.x < 64) {
    unsigned long long m[5] = {0, 0, 0, 0, 0};
#pragma unroll
    for (int g = 0; g < 4; ++g)
#pragma unroll
      for (int j = 0; j < 5; ++j) ins5(m, lds[(threadIdx.x * 4 + g) * 5 + j]);
#pragma unroll
    for (int off = 1; off < 64; off <<= 1) {   // butterfly merge of sorted 5-lists
      unsigned long long o[5];
#pragma unroll
      for (int j = 0; j < 5; ++j) o[j] = __shfl_xor(m[j], off, 64);
      unsigned long long out[5];
      int a = 0, b2 = 0;
#pragma unroll
      for (int r = 0; r < 5; ++r) out[r] = (m[a] >= o[b2]) ? m[a++] : o[b2++];
#pragma unroll
      for (int j = 0; j < 5; ++j) m[j] = out[j];
    }
    if (threadIdx.x == 0) {
      float v[5]; uint32_t ix[5];
#pragma unroll
      for (int j = 0; j < 5; ++j) { v[j] = keyval(m[j]); ix[j] = keyidx(m[j]); }
      float mx = v[0];     // m[0] is the max
      float e[5], Z = 0.f;
#pragma unroll
      for (int j = 0; j < 5; ++j) { e[j] = expf((v[j] - mx) * (1.0f / 3.0f)); Z += e[j]; }
      float invZ = 1.0f / Z;
      size_t row = (size_t)k * BROWS + b;
#pragma unroll
      for (int j = 0; j < 5; ++j) soft[row * NCOLS + ix[j]] = e[j] * invZ;
    }
  }
}

extern "C" void kernel_launch(void* const* d_in, const int* in_sizes, int n_in,
                              void* d_out, int out_size, void* d_ws, size_t ws_size,
                              hipStream_t stream) {
  const float* part = (const float*)d_in[0];    // [6,128,256]
  const float* memB = (const float*)d_in[1];    // [6,65536,256]
  float* soft = (float*)d_out;                                  // [6,128,65536]
  float* sim = soft + (size_t)KP * BROWS * NCOLS;               // [6,128,65536]

  char* wsA = (char*)d_ws;                                      // 6*8*16384 = 786432 B
  unsigned long long* cand = (unsigned long long*)(wsA + (size_t)KP * NCH * 16384);

  norm_split<<<KP * BROWS, 256, 0, stream>>>(part, wsA);
  dim3 g1(NBLK, KP);
  gemm_topk<<<g1, T1, 0, stream>>>(memB, wsA, soft, sim, cand);
  topk_softmax<<<KP * BROWS, 256, 0, stream>>>(cand, soft);
}